// Round 3
// baseline (411.153 us; speedup 1.0000x reference)
//
#include <hip/hip_runtime.h>
#include <hip/hip_bf16.h>

// Problem constants
#define B_    2
#define S_    2048
#define E_    2048
#define H_    16
#define HKV_  4
#define D_    128
#define NTOK  4096      // B_*S_
#define KVDIM 512       // HKV_*D_

typedef __bf16 bf16x8 __attribute__((ext_vector_type(8)));
typedef __bf16 bf16x4 __attribute__((ext_vector_type(4)));
typedef float  f32x4  __attribute__((ext_vector_type(4)));

__device__ __forceinline__ void async_copy16(const void* g, void* l) {
  // 16B per lane; LDS dest = wave-uniform base + lane*16 (m104/m108 semantics)
  __builtin_amdgcn_global_load_lds(
      (const __attribute__((address_space(1))) unsigned int*)g,
      (__attribute__((address_space(3))) unsigned int*)l, 16, 0, 0);
}

// ---------------------------------------------------------------------------
// Fused 4-weight transpose+convert: fp32 [R][C] -> bf16 [C][R], z selects W.
// ---------------------------------------------------------------------------
__global__ __launch_bounds__(256) void transpose_all(
    const float* __restrict__ Wq, const float* __restrict__ Wk,
    const float* __restrict__ Wv, const float* __restrict__ Wo,
    __bf16* __restrict__ WTq, __bf16* __restrict__ WTk,
    __bf16* __restrict__ WTv, __bf16* __restrict__ WoT) {
  const float* in;
  __bf16* out;
  int C;
  switch (blockIdx.z) {
    case 0:  in = Wq; out = WTq; C = E_;   break;
    case 1:  in = Wk; out = WTk; C = KVDIM; break;
    case 2:  in = Wv; out = WTv; C = KVDIM; break;
    default: in = Wo; out = WoT; C = E_;   break;
  }
  const int c0 = blockIdx.x * 32;
  if (c0 >= C) return;  // uniform early-exit (idle z=1/2 blocks)
  const int r0 = blockIdx.y * 32;
  __shared__ float t[32][33];
  const int tr = threadIdx.x >> 3;        // 0..31
  const int tc = (threadIdx.x & 7) * 4;   // 0..28 step 4
  const float* ip = in + (size_t)(r0 + tr) * C + c0 + tc;
#pragma unroll
  for (int i = 0; i < 4; ++i) t[tr][tc + i] = ip[i];
  __syncthreads();
  __bf16* op = out + (size_t)(c0 + tr) * E_ + r0 + tc;  // R==E_ for all
#pragma unroll
  for (int i = 0; i < 4; ++i) op[i] = (__bf16)t[tc + i][tr];
}

// ---------------------------------------------------------------------------
// fp32 -> bf16 elementwise convert (query staging for pipelined GEMM).
// ---------------------------------------------------------------------------
__global__ __launch_bounds__(256) void convert_q(const float* __restrict__ in,
                                                 __bf16* __restrict__ ob) {
  const size_t i = ((size_t)blockIdx.x * 256 + threadIdx.x) * 8;
  const f32x4 a0 = *(const f32x4*)(in + i);
  const f32x4 a1 = *(const f32x4*)(in + i + 4);
  bf16x8 v;
#pragma unroll
  for (int j = 0; j < 4; ++j) { v[j] = (__bf16)a0[j]; v[4 + j] = (__bf16)a1[j]; }
  *(bf16x8*)(ob + i) = v;
}

// ---------------------------------------------------------------------------
// Fine-grained pipelined GEMM (T2+T3+T4+T5, m196/m198/m201 8-phase port):
// C = A(bf16,[M][K]) @ Bt(bf16,[N][K])^T. BM=128, BN=256, BK=64, 512 thr
// (8 waves 2m x 4n, per-wave 64x64). 2 K-tile LDS buffers (96 KB).
// Two phases per K-tile:
//   P0: ds_read af(f=0,1)+bf(all) [12 b128] | issue A-stage(t+1->other buf)
//       | barrier | lgkmcnt(0)+sched_barrier | setprio1 16 MFMA setprio0
//       | barrier  (closes B region of buf[t&1])
//   P1: ds_read af(f=2,3) [4 b128] | issue B-stage(t+2->buf[t&1])
//       | barrier | lgkmcnt(0)+sched_barrier | setprio1 16 MFMA setprio0
//       | gate: vmcnt(4)+barrier  (tile t+1 landed; B(t+2)'s 4 in flight)
// Region safety: A(t+1) target last read at P1(t-1), whose ds_reads complete
// before each wave's lgkmcnt(0); gate barrier closes them block-wide.
// B(t+2) target last read at P0(t), closed by P0's post-MFMA barrier.
// ---------------------------------------------------------------------------
__global__ __launch_bounds__(512, 1) void gemm_pipe(
    const __bf16* __restrict__ A, const __bf16* __restrict__ Bt,
    float* __restrict__ Cf, __bf16* __restrict__ Cb, int M, int N, int K,
    int epi) {
  // buf layout: [2][A 128*64 | B 256*64] bf16 = 2 * 24576 elems = 96 KB
  __shared__ __align__(16) __bf16 lds[2 * 24576];

  const int n0 = blockIdx.x * 256;
  const int m0 = blockIdx.y * 128;
  const int tid = threadIdx.x;
  const int w = tid >> 6;
  const int lane = tid & 63;
  const int quad = lane >> 4;
  const int l16 = lane & 15;
  const int wm = w >> 2;      // 0..1
  const int wn = w & 3;       // 0..3
  const int lr = lane >> 3;   // 0..7 (staging row within 8-row group)
  const int ls = lane & 7;    // staging 16B slot

  // Per-thread pre-swizzled global source pointers; advance 64 elems/stage.
  const __bf16* pa[2];
  const __bf16* pb[4];
#pragma unroll
  for (int r = 0; r < 2; ++r) {
    const int row = r * 64 + w * 8 + lr;
    pa[r] = A + (size_t)(m0 + row) * K + ((ls ^ (row & 7)) * 8);
  }
#pragma unroll
  for (int r = 0; r < 4; ++r) {
    const int row = r * 64 + w * 8 + lr;
    pb[r] = Bt + (size_t)(n0 + row) * K + ((ls ^ (row & 7)) * 8);
  }

  auto stageA = [&](int bufi) {
    __bf16* base = lds + bufi * 24576;
#pragma unroll
    for (int r = 0; r < 2; ++r) {
      async_copy16(pa[r], base + (size_t)(r * 64 + w * 8) * 64);
      pa[r] += 64;
    }
  };
  auto stageB = [&](int bufi) {
    __bf16* base = lds + bufi * 24576 + 8192;
#pragma unroll
    for (int r = 0; r < 4; ++r) {
      async_copy16(pb[r], base + (size_t)(r * 64 + w * 8) * 64);
      pb[r] += 64;
    }
  };

  f32x4 acc[4][4] = {};
  const int NT = K >> 6;
  const int xr = l16 & 7;

  // Prologue: tile0 (A+B) + tile1 (B only; A(1) issued at P0(0)).
  stageA(0);            // 2 loads
  stageB(0);            // 4 loads
  stageB(1);            // 4 loads
  asm volatile("s_waitcnt vmcnt(4)" ::: "memory");  // tile0 landed
  __builtin_amdgcn_s_barrier();

  for (int t = 0; t < NT; ++t) {
    const __bf16* lA = lds + (t & 1) * 24576;
    const __bf16* lB = lA + 8192;

    // ======== P0: f-half 0 ========
    bf16x8 af[2][2], bfr[4][2];
#pragma unroll
    for (int f = 0; f < 2; ++f) {
      const int rowb = (wm * 64 + f * 16 + l16) * 64;
#pragma unroll
      for (int ks = 0; ks < 2; ++ks)
        af[f][ks] = *(const bf16x8*)&lA[rowb + (((ks * 4 + quad) ^ xr) * 8)];
    }
#pragma unroll
    for (int g = 0; g < 4; ++g) {
      const int rowb = (wn * 64 + g * 16 + l16) * 64;
#pragma unroll
      for (int ks = 0; ks < 2; ++ks)
        bfr[g][ks] = *(const bf16x8*)&lB[rowb + (((ks * 4 + quad) ^ xr) * 8)];
    }
    if (t + 1 < NT) stageA((t + 1) & 1);  // A region of other buf is free
    __builtin_amdgcn_s_barrier();
    asm volatile("s_waitcnt lgkmcnt(0)" ::: "memory");
    __builtin_amdgcn_sched_barrier(0);
    __builtin_amdgcn_s_setprio(1);
#pragma unroll
    for (int f = 0; f < 2; ++f)
#pragma unroll
      for (int g = 0; g < 4; ++g) {
        acc[f][g] = __builtin_amdgcn_mfma_f32_16x16x32_bf16(af[f][0], bfr[g][0],
                                                            acc[f][g], 0, 0, 0);
        acc[f][g] = __builtin_amdgcn_mfma_f32_16x16x32_bf16(af[f][1], bfr[g][1],
                                                            acc[f][g], 0, 0, 0);
      }
    __builtin_amdgcn_s_setprio(0);
    __builtin_amdgcn_s_barrier();  // closes B region of buf[t&1]

    // ======== P1: f-half 1 ========
    bf16x8 ah[2][2];
#pragma unroll
    for (int f = 0; f < 2; ++f) {
      const int rowb = (wm * 64 + (f + 2) * 16 + l16) * 64;
#pragma unroll
      for (int ks = 0; ks < 2; ++ks)
        ah[f][ks] = *(const bf16x8*)&lA[rowb + (((ks * 4 + quad) ^ xr) * 8)];
    }
    if (t + 2 < NT) stageB(t & 1);  // B region of buf[t&1] freed by P0 close
    __builtin_amdgcn_s_barrier();
    asm volatile("s_waitcnt lgkmcnt(0)" ::: "memory");
    __builtin_amdgcn_sched_barrier(0);
    __builtin_amdgcn_s_setprio(1);
#pragma unroll
    for (int f = 0; f < 2; ++f)
#pragma unroll
      for (int g = 0; g < 4; ++g) {
        acc[f + 2][g] = __builtin_amdgcn_mfma_f32_16x16x32_bf16(
            ah[f][0], bfr[g][0], acc[f + 2][g], 0, 0, 0);
        acc[f + 2][g] = __builtin_amdgcn_mfma_f32_16x16x32_bf16(
            ah[f][1], bfr[g][1], acc[f + 2][g], 0, 0, 0);
      }
    __builtin_amdgcn_s_setprio(0);

    // K-tile gate: next tile's data must have landed before P0(t+1) reads.
    if (t + 2 < NT) {
      asm volatile("s_waitcnt vmcnt(4)" ::: "memory");
      __builtin_amdgcn_s_barrier();
    } else if (t + 1 < NT) {
      asm volatile("s_waitcnt vmcnt(0)" ::: "memory");
      __builtin_amdgcn_s_barrier();
    }
  }

  // C/D layout: col = lane&15 (n), row = quad*4 + reg (m). [m89/m91]
#pragma unroll
  for (int f = 0; f < 4; ++f) {
#pragma unroll
    for (int g = 0; g < 4; ++g) {
#pragma unroll
      for (int r = 0; r < 4; ++r) {
        const int m = m0 + wm * 64 + f * 16 + quad * 4 + r;
        const int n = n0 + wn * 64 + g * 16 + l16;
        if (epi == 0) Cf[(size_t)m * N + n] = acc[f][g][r];
        else          Cb[(size_t)m * N + n] = (__bf16)acc[f][g][r];
      }
    }
  }
}

// ---------------------------------------------------------------------------
// K/V projection (old m97-style kernel, fp32 A converted during staging).
// bx 0..3: key @ WTk -> Kp; bx 4..7: value @ WTv -> Vt (scatter [b][hkv][d][s])
// ---------------------------------------------------------------------------
__global__ __launch_bounds__(256, 2) void gemm_kv(
    const float* __restrict__ key, const float* __restrict__ value,
    const __bf16* __restrict__ WTk, const __bf16* __restrict__ WTv,
    __bf16* __restrict__ Kp, __bf16* __restrict__ Vt) {
  __shared__ __align__(16) __bf16 As[128 * 32];
  __shared__ __align__(16) __bf16 Bs[128 * 32];

  const int bx = blockIdx.x;  // 0..7
  const float* A;
  const __bf16* Bt;
  int n0, epi;
  if (bx < 4) { A = key;   Bt = WTk; n0 = bx * 128;       epi = 0; }
  else        { A = value; Bt = WTv; n0 = (bx - 4) * 128; epi = 1; }
  const int m0 = blockIdx.y * 128;
  const int K = E_;
  const int N = KVDIM;

  const int tid = threadIdx.x;
  const int w = tid >> 6;
  const int lane = tid & 63;
  const int quad = lane >> 4;
  const int l16 = lane & 15;
  const int wr = w >> 1, wc = w & 1;
  const int brow = lane >> 2;
  const int bcol = (lane & 3) * 8;
  const int arow = lane >> 2;
  const int acol = (lane & 3) * 8;

  f32x4 acc[4][4] = {};

  for (int k0 = 0; k0 < K; k0 += 32) {
    __syncthreads();
#pragma unroll
    for (int c = 0; c < 2; ++c) {
      const int chunk = w * 2 + c;
      const int row = chunk * 16 + brow;
      async_copy16(Bt + (size_t)(n0 + row) * K + k0 + bcol, &Bs[chunk * 512]);
    }
#pragma unroll
    for (int s = 0; s < 2; ++s) {
      const int row = w * 32 + s * 16 + arow;
      const float* src = A + (size_t)(m0 + row) * K + k0 + acol;
      const f32x4 a0 = *(const f32x4*)src;
      const f32x4 a1 = *(const f32x4*)(src + 4);
      bf16x8 v;
#pragma unroll
      for (int j = 0; j < 4; ++j) { v[j] = (__bf16)a0[j]; v[4 + j] = (__bf16)a1[j]; }
      *(bf16x8*)&As[row * 32 + acol] = v;
    }
    __syncthreads();
    bf16x8 af[4], bfr[4];
#pragma unroll
    for (int i = 0; i < 4; ++i)
      af[i] = *(const bf16x8*)&As[(wr * 64 + i * 16 + l16) * 32 + quad * 8];
#pragma unroll
    for (int j = 0; j < 4; ++j)
      bfr[j] = *(const bf16x8*)&Bs[(wc * 64 + j * 16 + l16) * 32 + quad * 8];
#pragma unroll
    for (int i = 0; i < 4; ++i)
#pragma unroll
      for (int j = 0; j < 4; ++j)
        acc[i][j] = __builtin_amdgcn_mfma_f32_16x16x32_bf16(af[i], bfr[j],
                                                            acc[i][j], 0, 0, 0);
  }

#pragma unroll
  for (int i = 0; i < 4; ++i) {
#pragma unroll
    for (int j = 0; j < 4; ++j) {
#pragma unroll
      for (int r = 0; r < 4; ++r) {
        const int m = m0 + wr * 64 + i * 16 + quad * 4 + r;
        const int n = n0 + wc * 64 + j * 16 + l16;
        if (epi == 0) {
          Kp[(size_t)m * N + n] = (__bf16)acc[i][j][r];
        } else {
          const int b = m >> 11, s = m & (S_ - 1);
          Vt[((size_t)((b * HKV_ + (n >> 7)) * D_ + (n & (D_ - 1)))) * S_ + s] =
              (__bf16)acc[i][j][r];
        }
      }
    }
  }
}

// ---------------------------------------------------------------------------
// Flash attention: block = 128 q-rows of one (b,h).
// ---------------------------------------------------------------------------
__global__ __launch_bounds__(256, 2) void attn_kernel(
    const __bf16* __restrict__ Q, const __bf16* __restrict__ Kp,
    const __bf16* __restrict__ Vt, const float* __restrict__ mask,
    __bf16* __restrict__ Oa) {
  __shared__ __align__(16) __bf16 K_lds[64][136];
  __shared__ __align__(16) __bf16 V_lds[128][72];
  __shared__ __align__(16) __bf16 P_lds[4][32][72];

  const int tid = threadIdx.x;
  const int w = tid >> 6, lane = tid & 63, quad = lane >> 4, l16 = lane & 15;
  const int bh = blockIdx.y;
  const int b = bh >> 4, h = bh & 15, hkv = h >> 2;
  const int q0 = blockIdx.x * 128 + w * 32;

  const __bf16* qbase = Q + (size_t)(b * S_ + q0) * E_ + h * D_;
  bf16x8 qf[2][4];
#pragma unroll
  for (int m = 0; m < 2; ++m)
#pragma unroll
    for (int ks = 0; ks < 4; ++ks)
      qf[m][ks] = *(const bf16x8*)(qbase + (size_t)(m * 16 + l16) * E_ +
                                   ks * 32 + quad * 8);

  const __bf16* kbase = Kp + (size_t)(b * S_) * KVDIM + hkv * D_;
  const __bf16* vbase = Vt + (size_t)((b * HKV_ + hkv) * D_) * S_;
  const float* mbase = mask + b * S_;

  f32x4 o[2][8] = {};
  f32x4 lsum[2] = {};
  const float scale = 0.08838834764831845f;  // 1/sqrt(128)

  for (int kt = 0; kt < S_; kt += 64) {
    __syncthreads();
#pragma unroll
    for (int i = 0; i < 4; ++i) {
      const int r = w * 16 + i * 4 + (lane >> 4);
      bf16x8 kv = *(const bf16x8*)(kbase + (size_t)(kt + r) * KVDIM +
                                   (lane & 15) * 8);
      *(bf16x8*)&K_lds[r][(lane & 15) * 8] = kv;
    }
#pragma unroll
    for (int i = 0; i < 4; ++i) {
      const int r = w * 32 + i * 8 + (lane >> 3);
      bf16x8 vv = *(const bf16x8*)(vbase + (size_t)r * S_ + kt +
                                   (lane & 7) * 8);
      *(bf16x8*)&V_lds[r][(lane & 7) * 8] = vv;
    }
    __syncthreads();

    f32x4 s[2][4] = {};
    __builtin_amdgcn_s_setprio(1);
#pragma unroll
    for (int ks = 0; ks < 4; ++ks) {
#pragma unroll
      for (int n = 0; n < 4; ++n) {
        bf16x8 kf = *(const bf16x8*)&K_lds[n * 16 + l16][ks * 32 + quad * 8];
        s[0][n] = __builtin_amdgcn_mfma_f32_16x16x32_bf16(qf[0][ks], kf,
                                                          s[0][n], 0, 0, 0);
        s[1][n] = __builtin_amdgcn_mfma_f32_16x16x32_bf16(qf[1][ks], kf,
                                                          s[1][n], 0, 0, 0);
      }
    }
    __builtin_amdgcn_s_setprio(0);

    float bias[4];
#pragma unroll
    for (int n = 0; n < 4; ++n)
      bias[n] = (1.0f - mbase[kt + n * 16 + l16]) * -1e9f;
#pragma unroll
    for (int m = 0; m < 2; ++m) {
#pragma unroll
      for (int n = 0; n < 4; ++n) {
#pragma unroll
        for (int r = 0; r < 4; ++r) {
          const float p = __expf(s[m][n][r] * scale + bias[n]);
          lsum[m][r] += p;
          P_lds[w][m * 16 + quad * 4 + r][n * 16 + l16] = (__bf16)p;
        }
      }
    }

    __builtin_amdgcn_s_setprio(1);
#pragma unroll
    for (int ks2 = 0; ks2 < 2; ++ks2) {
      bf16x8 pa[2];
#pragma unroll
      for (int m = 0; m < 2; ++m)
        pa[m] = *(const bf16x8*)&P_lds[w][m * 16 + l16][ks2 * 32 + quad * 8];
#pragma unroll
      for (int dt = 0; dt < 8; ++dt) {
        bf16x8 vf = *(const bf16x8*)&V_lds[dt * 16 + l16][ks2 * 32 + quad * 8];
        o[0][dt] = __builtin_amdgcn_mfma_f32_16x16x32_bf16(pa[0], vf,
                                                           o[0][dt], 0, 0, 0);
        o[1][dt] = __builtin_amdgcn_mfma_f32_16x16x32_bf16(pa[1], vf,
                                                           o[1][dt], 0, 0, 0);
      }
    }
    __builtin_amdgcn_s_setprio(0);
  }

  __bf16* obase = Oa + (size_t)(b * S_ + q0) * E_ + h * D_;
#pragma unroll
  for (int m = 0; m < 2; ++m) {
#pragma unroll
    for (int r = 0; r < 4; ++r) {
      float v = lsum[m][r];
#pragma unroll
      for (int off = 1; off < 16; off <<= 1) v += __shfl_xor(v, off);
      const float inv = 1.0f / v;
#pragma unroll
      for (int dt = 0; dt < 8; ++dt)
        obase[(size_t)(m * 16 + quad * 4 + r) * E_ + dt * 16 + l16] =
            (__bf16)(o[m][dt][r] * inv);
    }
  }
}

// ---------------------------------------------------------------------------
extern "C" void kernel_launch(void* const* d_in, const int* in_sizes, int n_in,
                              void* d_out, int out_size, void* d_ws,
                              size_t ws_size, hipStream_t stream) {
  const float* query = (const float*)d_in[0];
  const float* key   = (const float*)d_in[1];
  const float* value = (const float*)d_in[2];
  const float* mask  = (const float*)d_in[3];
  const float* Wq    = (const float*)d_in[4];
  const float* Wk    = (const float*)d_in[5];
  const float* Wv    = (const float*)d_in[6];
  const float* Wo    = (const float*)d_in[7];
  float* out = (float*)d_out;

  // Workspace 48 MB (known-safe), bf16 elements:
  //   Qp 16MB | Kp 4MB | Vt 4MB | WoT 8MB | WTq 8MB | WTk 2MB | WTv 2MB | sp 4MB
  // Attn (16MB) overlaps [WTq|WTk|WTv|spare] — consumed before attention runs.
  // qb (bf16 query, 16MB) lives in d_out (32MB fp32) — fully overwritten by
  // the final O-projection, consumed before it.
  __bf16* ws   = (__bf16*)d_ws;
  __bf16* Qp   = ws;                           // @ 0
  __bf16* Kp   = Qp + (size_t)NTOK * E_;       // @ 16MB
  __bf16* Vt   = Kp + (size_t)NTOK * KVDIM;    // @ 20MB
  __bf16* WoT  = Vt + (size_t)NTOK * KVDIM;    // @ 24MB
  __bf16* WTq  = WoT + (size_t)E_ * E_;        // @ 32MB
  __bf16* WTk  = WTq + (size_t)E_ * E_;        // @ 40MB
  __bf16* WTv  = WTk + (size_t)KVDIM * E_;     // @ 42MB
  __bf16* Attn = WTq;                          // @ 32MB (16MB, reuse)
  __bf16* qb   = (__bf16*)d_out;               // 16MB scratch in output buf

  // 1) all weight transposes in one launch
  transpose_all<<<dim3(64, 64, 4), 256, 0, stream>>>(Wq, Wk, Wv, Wo,
                                                     WTq, WTk, WTv, WoT);
  // 2) query fp32 -> bf16 (enables global_load_lds A-path in gemm_pipe)
  convert_q<<<dim3(4096), 256, 0, stream>>>(query, qb);
  // 3) K/V projections (old structure, fp32 A), 8x32 = 256 blocks
  gemm_kv<<<dim3(8, 32), 256, 0, stream>>>(key, value, WTk, WTv, Kp, Vt);
  // 4) Q projection via pipelined GEMM: qb @ WTq -> Qp (bf16 epilogue)
  gemm_pipe<<<dim3(E_ / 256, NTOK / 128), 512, 0, stream>>>(
      qb, WTq, nullptr, Qp, NTOK, E_, E_, 1);
  // 5) attention -> Attn (clobbers WTq/k/v, already consumed)
  attn_kernel<<<dim3(S_ / 128, B_ * H_), 256, 0, stream>>>(Qp, Kp, Vt, mask,
                                                           Attn);
  // 6) output projection via pipelined GEMM (fp32 epilogue straight to d_out)
  gemm_pipe<<<dim3(E_ / 256, NTOK / 128), 512, 0, stream>>>(
      Attn, WoT, out, nullptr, NTOK, E_, E_, 0);
}

// Round 4
// 408.282 us; speedup vs baseline: 1.0070x; 1.0070x over previous
//
#include <hip/hip_runtime.h>
#include <hip/hip_bf16.h>

// Problem constants
#define B_    2
#define S_    2048
#define E_    2048
#define H_    16
#define HKV_  4
#define D_    128
#define NTOK  4096      // B_*S_
#define KVDIM 512       // HKV_*D_

typedef __bf16 bf16x8 __attribute__((ext_vector_type(8)));
typedef __bf16 bf16x4 __attribute__((ext_vector_type(4)));
typedef float  f32x4  __attribute__((ext_vector_type(4)));

__device__ __forceinline__ void async_copy16(const void* g, void* l) {
  // 16B per lane; LDS dest = wave-uniform base + lane*16 (m104/m108 semantics)
  __builtin_amdgcn_global_load_lds(
      (const __attribute__((address_space(1))) unsigned int*)g,
      (__attribute__((address_space(3))) unsigned int*)l, 16, 0, 0);
}

// ---------------------------------------------------------------------------
// Fused 4-weight transpose+convert: fp32 [R][C] -> bf16 [C][R], z selects W.
// ---------------------------------------------------------------------------
__global__ __launch_bounds__(256) void transpose_all(
    const float* __restrict__ Wq, const float* __restrict__ Wk,
    const float* __restrict__ Wv, const float* __restrict__ Wo,
    __bf16* __restrict__ WTq, __bf16* __restrict__ WTk,
    __bf16* __restrict__ WTv, __bf16* __restrict__ WoT) {
  const float* in;
  __bf16* out;
  int C;
  switch (blockIdx.z) {
    case 0:  in = Wq; out = WTq; C = E_;   break;
    case 1:  in = Wk; out = WTk; C = KVDIM; break;
    case 2:  in = Wv; out = WTv; C = KVDIM; break;
    default: in = Wo; out = WoT; C = E_;   break;
  }
  const int c0 = blockIdx.x * 32;
  if (c0 >= C) return;  // uniform early-exit (idle z=1/2 blocks)
  const int r0 = blockIdx.y * 32;
  __shared__ float t[32][33];
  const int tr = threadIdx.x >> 3;        // 0..31
  const int tc = (threadIdx.x & 7) * 4;   // 0..28 step 4
  const float* ip = in + (size_t)(r0 + tr) * C + c0 + tc;
#pragma unroll
  for (int i = 0; i < 4; ++i) t[tr][tc + i] = ip[i];
  __syncthreads();
  __bf16* op = out + (size_t)(c0 + tr) * E_ + r0 + tc;  // R==E_ for all
#pragma unroll
  for (int i = 0; i < 4; ++i) op[i] = (__bf16)t[tc + i][tr];
}

// ---------------------------------------------------------------------------
// fp32 -> bf16 elementwise convert (query staging for pipelined GEMM).
// ---------------------------------------------------------------------------
__global__ __launch_bounds__(256) void convert_q(const float* __restrict__ in,
                                                 __bf16* __restrict__ ob) {
  const size_t i = ((size_t)blockIdx.x * 256 + threadIdx.x) * 8;
  const f32x4 a0 = *(const f32x4*)(in + i);
  const f32x4 a1 = *(const f32x4*)(in + i + 4);
  bf16x8 v;
#pragma unroll
  for (int j = 0; j < 4; ++j) { v[j] = (__bf16)a0[j]; v[4 + j] = (__bf16)a1[j]; }
  *(bf16x8*)(ob + i) = v;
}

// ---------------------------------------------------------------------------
// Fine-grained pipelined GEMM (unchanged from round 3 — passed, frozen).
// C = A(bf16,[M][K]) @ Bt(bf16,[N][K])^T. BM=128, BN=256, BK=64, 512 thr.
// ---------------------------------------------------------------------------
__global__ __launch_bounds__(512, 1) void gemm_pipe(
    const __bf16* __restrict__ A, const __bf16* __restrict__ Bt,
    float* __restrict__ Cf, __bf16* __restrict__ Cb, int M, int N, int K,
    int epi) {
  // buf layout: [2][A 128*64 | B 256*64] bf16 = 2 * 24576 elems = 96 KB
  __shared__ __align__(16) __bf16 lds[2 * 24576];

  const int n0 = blockIdx.x * 256;
  const int m0 = blockIdx.y * 128;
  const int tid = threadIdx.x;
  const int w = tid >> 6;
  const int lane = tid & 63;
  const int quad = lane >> 4;
  const int l16 = lane & 15;
  const int wm = w >> 2;      // 0..1
  const int wn = w & 3;       // 0..3
  const int lr = lane >> 3;   // 0..7 (staging row within 8-row group)
  const int ls = lane & 7;    // staging 16B slot

  const __bf16* pa[2];
  const __bf16* pb[4];
#pragma unroll
  for (int r = 0; r < 2; ++r) {
    const int row = r * 64 + w * 8 + lr;
    pa[r] = A + (size_t)(m0 + row) * K + ((ls ^ (row & 7)) * 8);
  }
#pragma unroll
  for (int r = 0; r < 4; ++r) {
    const int row = r * 64 + w * 8 + lr;
    pb[r] = Bt + (size_t)(n0 + row) * K + ((ls ^ (row & 7)) * 8);
  }

  auto stageA = [&](int bufi) {
    __bf16* base = lds + bufi * 24576;
#pragma unroll
    for (int r = 0; r < 2; ++r) {
      async_copy16(pa[r], base + (size_t)(r * 64 + w * 8) * 64);
      pa[r] += 64;
    }
  };
  auto stageB = [&](int bufi) {
    __bf16* base = lds + bufi * 24576 + 8192;
#pragma unroll
    for (int r = 0; r < 4; ++r) {
      async_copy16(pb[r], base + (size_t)(r * 64 + w * 8) * 64);
      pb[r] += 64;
    }
  };

  f32x4 acc[4][4] = {};
  const int NT = K >> 6;
  const int xr = l16 & 7;

  stageA(0);            // 2 loads
  stageB(0);            // 4 loads
  stageB(1);            // 4 loads
  asm volatile("s_waitcnt vmcnt(4)" ::: "memory");  // tile0 landed
  __builtin_amdgcn_s_barrier();

  for (int t = 0; t < NT; ++t) {
    const __bf16* lA = lds + (t & 1) * 24576;
    const __bf16* lB = lA + 8192;

    // ======== P0: f-half 0 ========
    bf16x8 af[2][2], bfr[4][2];
#pragma unroll
    for (int f = 0; f < 2; ++f) {
      const int rowb = (wm * 64 + f * 16 + l16) * 64;
#pragma unroll
      for (int ks = 0; ks < 2; ++ks)
        af[f][ks] = *(const bf16x8*)&lA[rowb + (((ks * 4 + quad) ^ xr) * 8)];
    }
#pragma unroll
    for (int g = 0; g < 4; ++g) {
      const int rowb = (wn * 64 + g * 16 + l16) * 64;
#pragma unroll
      for (int ks = 0; ks < 2; ++ks)
        bfr[g][ks] = *(const bf16x8*)&lB[rowb + (((ks * 4 + quad) ^ xr) * 8)];
    }
    if (t + 1 < NT) stageA((t + 1) & 1);  // A region of other buf is free
    __builtin_amdgcn_s_barrier();
    asm volatile("s_waitcnt lgkmcnt(0)" ::: "memory");
    __builtin_amdgcn_sched_barrier(0);
    __builtin_amdgcn_s_setprio(1);
#pragma unroll
    for (int f = 0; f < 2; ++f)
#pragma unroll
      for (int g = 0; g < 4; ++g) {
        acc[f][g] = __builtin_amdgcn_mfma_f32_16x16x32_bf16(af[f][0], bfr[g][0],
                                                            acc[f][g], 0, 0, 0);
        acc[f][g] = __builtin_amdgcn_mfma_f32_16x16x32_bf16(af[f][1], bfr[g][1],
                                                            acc[f][g], 0, 0, 0);
      }
    __builtin_amdgcn_s_setprio(0);
    __builtin_amdgcn_s_barrier();  // closes B region of buf[t&1]

    // ======== P1: f-half 1 ========
    bf16x8 ah[2][2];
#pragma unroll
    for (int f = 0; f < 2; ++f) {
      const int rowb = (wm * 64 + (f + 2) * 16 + l16) * 64;
#pragma unroll
      for (int ks = 0; ks < 2; ++ks)
        ah[f][ks] = *(const bf16x8*)&lA[rowb + (((ks * 4 + quad) ^ xr) * 8)];
    }
    if (t + 2 < NT) stageB(t & 1);  // B region of buf[t&1] freed by P0 close
    __builtin_amdgcn_s_barrier();
    asm volatile("s_waitcnt lgkmcnt(0)" ::: "memory");
    __builtin_amdgcn_sched_barrier(0);
    __builtin_amdgcn_s_setprio(1);
#pragma unroll
    for (int f = 0; f < 2; ++f)
#pragma unroll
      for (int g = 0; g < 4; ++g) {
        acc[f + 2][g] = __builtin_amdgcn_mfma_f32_16x16x32_bf16(
            ah[f][0], bfr[g][0], acc[f + 2][g], 0, 0, 0);
        acc[f + 2][g] = __builtin_amdgcn_mfma_f32_16x16x32_bf16(
            ah[f][1], bfr[g][1], acc[f + 2][g], 0, 0, 0);
      }
    __builtin_amdgcn_s_setprio(0);

    if (t + 2 < NT) {
      asm volatile("s_waitcnt vmcnt(4)" ::: "memory");
      __builtin_amdgcn_s_barrier();
    } else if (t + 1 < NT) {
      asm volatile("s_waitcnt vmcnt(0)" ::: "memory");
      __builtin_amdgcn_s_barrier();
    }
  }

  // C/D layout: col = lane&15 (n), row = quad*4 + reg (m). [m89/m91]
#pragma unroll
  for (int f = 0; f < 4; ++f) {
#pragma unroll
    for (int g = 0; g < 4; ++g) {
#pragma unroll
      for (int r = 0; r < 4; ++r) {
        const int m = m0 + wm * 64 + f * 16 + quad * 4 + r;
        const int n = n0 + wn * 64 + g * 16 + l16;
        if (epi == 0) Cf[(size_t)m * N + n] = acc[f][g][r];
        else          Cb[(size_t)m * N + n] = (__bf16)acc[f][g][r];
      }
    }
  }
}

// ---------------------------------------------------------------------------
// K/V projection (m97-style kernel, fp32 A converted during staging; frozen).
// ---------------------------------------------------------------------------
__global__ __launch_bounds__(256, 2) void gemm_kv(
    const float* __restrict__ key, const float* __restrict__ value,
    const __bf16* __restrict__ WTk, const __bf16* __restrict__ WTv,
    __bf16* __restrict__ Kp, __bf16* __restrict__ Vt) {
  __shared__ __align__(16) __bf16 As[128 * 32];
  __shared__ __align__(16) __bf16 Bs[128 * 32];

  const int bx = blockIdx.x;  // 0..7
  const float* A;
  const __bf16* Bt;
  int n0, epi;
  if (bx < 4) { A = key;   Bt = WTk; n0 = bx * 128;       epi = 0; }
  else        { A = value; Bt = WTv; n0 = (bx - 4) * 128; epi = 1; }
  const int m0 = blockIdx.y * 128;
  const int K = E_;
  const int N = KVDIM;

  const int tid = threadIdx.x;
  const int w = tid >> 6;
  const int lane = tid & 63;
  const int quad = lane >> 4;
  const int l16 = lane & 15;
  const int wr = w >> 1, wc = w & 1;
  const int brow = lane >> 2;
  const int bcol = (lane & 3) * 8;
  const int arow = lane >> 2;
  const int acol = (lane & 3) * 8;

  f32x4 acc[4][4] = {};

  for (int k0 = 0; k0 < K; k0 += 32) {
    __syncthreads();
#pragma unroll
    for (int c = 0; c < 2; ++c) {
      const int chunk = w * 2 + c;
      const int row = chunk * 16 + brow;
      async_copy16(Bt + (size_t)(n0 + row) * K + k0 + bcol, &Bs[chunk * 512]);
    }
#pragma unroll
    for (int s = 0; s < 2; ++s) {
      const int row = w * 32 + s * 16 + arow;
      const float* src = A + (size_t)(m0 + row) * K + k0 + acol;
      const f32x4 a0 = *(const f32x4*)src;
      const f32x4 a1 = *(const f32x4*)(src + 4);
      bf16x8 v;
#pragma unroll
      for (int j = 0; j < 4; ++j) { v[j] = (__bf16)a0[j]; v[4 + j] = (__bf16)a1[j]; }
      *(bf16x8*)&As[row * 32 + acol] = v;
    }
    __syncthreads();
    bf16x8 af[4], bfr[4];
#pragma unroll
    for (int i = 0; i < 4; ++i)
      af[i] = *(const bf16x8*)&As[(wr * 64 + i * 16 + l16) * 32 + quad * 8];
#pragma unroll
    for (int j = 0; j < 4; ++j)
      bfr[j] = *(const bf16x8*)&Bs[(wc * 64 + j * 16 + l16) * 32 + quad * 8];
#pragma unroll
    for (int i = 0; i < 4; ++i)
#pragma unroll
      for (int j = 0; j < 4; ++j)
        acc[i][j] = __builtin_amdgcn_mfma_f32_16x16x32_bf16(af[i], bfr[j],
                                                            acc[i][j], 0, 0, 0);
  }

#pragma unroll
  for (int i = 0; i < 4; ++i) {
#pragma unroll
    for (int j = 0; j < 4; ++j) {
#pragma unroll
      for (int r = 0; r < 4; ++r) {
        const int m = m0 + wr * 64 + i * 16 + quad * 4 + r;
        const int n = n0 + wc * 64 + j * 16 + l16;
        if (epi == 0) {
          Kp[(size_t)m * N + n] = (__bf16)acc[i][j][r];
        } else {
          const int b = m >> 11, s = m & (S_ - 1);
          Vt[((size_t)((b * HKV_ + (n >> 7)) * D_ + (n & (D_ - 1)))) * S_ + s] =
              (__bf16)acc[i][j][r];
        }
      }
    }
  }
}

// ---------------------------------------------------------------------------
// Flash attention: block = 128 q-rows of one (b,h).
// Round 4: T14 async-STAGE split — next-tile K/V global loads issued into
// VGPRs right after the write-sync (in flight across QK+softmax+PV, ~2500
// cyc), ds_write'd at the top of the next iteration after the read-sync.
// LDS unchanged (single buffer); +32 VGPRs for kreg/vreg.
// ---------------------------------------------------------------------------
__global__ __launch_bounds__(256, 2) void attn_kernel(
    const __bf16* __restrict__ Q, const __bf16* __restrict__ Kp,
    const __bf16* __restrict__ Vt, const float* __restrict__ mask,
    __bf16* __restrict__ Oa) {
  __shared__ __align__(16) __bf16 K_lds[64][136];
  __shared__ __align__(16) __bf16 V_lds[128][72];
  __shared__ __align__(16) __bf16 P_lds[4][32][72];

  const int tid = threadIdx.x;
  const int w = tid >> 6, lane = tid & 63, quad = lane >> 4, l16 = lane & 15;
  const int bh = blockIdx.y;
  const int b = bh >> 4, h = bh & 15, hkv = h >> 2;
  const int q0 = blockIdx.x * 128 + w * 32;

  const __bf16* qbase = Q + (size_t)(b * S_ + q0) * E_ + h * D_;
  bf16x8 qf[2][4];
#pragma unroll
  for (int m = 0; m < 2; ++m)
#pragma unroll
    for (int ks = 0; ks < 4; ++ks)
      qf[m][ks] = *(const bf16x8*)(qbase + (size_t)(m * 16 + l16) * E_ +
                                   ks * 32 + quad * 8);

  const __bf16* kbase = Kp + (size_t)(b * S_) * KVDIM + hkv * D_;
  const __bf16* vbase = Vt + (size_t)((b * HKV_ + hkv) * D_) * S_;
  const float* mbase = mask + b * S_;

  // Staging geometry (same addressing as before, split issue/write):
  const int kr = w * 16 + (lane >> 4);        // K row base (+i*4)
  const int kc = (lane & 15) * 8;             // K col
  const int vr = w * 32 + (lane >> 3);        // V row base (+i*8)
  const int vc = (lane & 7) * 8;              // V col (within kt tile)

  bf16x8 kreg[4], vreg[4];
  auto fetch = [&](int kt) {
#pragma unroll
    for (int i = 0; i < 4; ++i)
      kreg[i] = *(const bf16x8*)(kbase + (size_t)(kt + kr + i * 4) * KVDIM + kc);
#pragma unroll
    for (int i = 0; i < 4; ++i)
      vreg[i] = *(const bf16x8*)(vbase + (size_t)(vr + i * 8) * S_ + kt + vc);
  };

  f32x4 o[2][8] = {};
  f32x4 lsum[2] = {};
  const float scale = 0.08838834764831845f;  // 1/sqrt(128)

  fetch(0);  // prologue prefetch

  for (int kt = 0; kt < S_; kt += 64) {
    // write current tile's regs -> LDS (prev iter's read-sync guarantees safe)
#pragma unroll
    for (int i = 0; i < 4; ++i)
      *(bf16x8*)&K_lds[kr + i * 4][kc] = kreg[i];
#pragma unroll
    for (int i = 0; i < 4; ++i)
      *(bf16x8*)&V_lds[vr + i * 8][vc] = vreg[i];
    __syncthreads();  // LDS(t) visible to all

    // T14: issue next tile's global loads NOW — hidden under compute below
    if (kt + 64 < S_) fetch(kt + 64);

    f32x4 s[2][4] = {};
    __builtin_amdgcn_s_setprio(1);
#pragma unroll
    for (int ks = 0; ks < 4; ++ks) {
#pragma unroll
      for (int n = 0; n < 4; ++n) {
        bf16x8 kf = *(const bf16x8*)&K_lds[n * 16 + l16][ks * 32 + quad * 8];
        s[0][n] = __builtin_amdgcn_mfma_f32_16x16x32_bf16(qf[0][ks], kf,
                                                          s[0][n], 0, 0, 0);
        s[1][n] = __builtin_amdgcn_mfma_f32_16x16x32_bf16(qf[1][ks], kf,
                                                          s[1][n], 0, 0, 0);
      }
    }
    __builtin_amdgcn_s_setprio(0);

    float bias[4];
#pragma unroll
    for (int n = 0; n < 4; ++n)
      bias[n] = (1.0f - mbase[kt + n * 16 + l16]) * -1e9f;
#pragma unroll
    for (int m = 0; m < 2; ++m) {
#pragma unroll
      for (int n = 0; n < 4; ++n) {
#pragma unroll
        for (int r = 0; r < 4; ++r) {
          const float p = __expf(s[m][n][r] * scale + bias[n]);
          lsum[m][r] += p;
          P_lds[w][m * 16 + quad * 4 + r][n * 16 + l16] = (__bf16)p;
        }
      }
    }

    __builtin_amdgcn_s_setprio(1);
#pragma unroll
    for (int ks2 = 0; ks2 < 2; ++ks2) {
      bf16x8 pa[2];
#pragma unroll
      for (int m = 0; m < 2; ++m)
        pa[m] = *(const bf16x8*)&P_lds[w][m * 16 + l16][ks2 * 32 + quad * 8];
#pragma unroll
      for (int dt = 0; dt < 8; ++dt) {
        bf16x8 vf = *(const bf16x8*)&V_lds[dt * 16 + l16][ks2 * 32 + quad * 8];
        o[0][dt] = __builtin_amdgcn_mfma_f32_16x16x32_bf16(pa[0], vf,
                                                           o[0][dt], 0, 0, 0);
        o[1][dt] = __builtin_amdgcn_mfma_f32_16x16x32_bf16(pa[1], vf,
                                                           o[1][dt], 0, 0, 0);
      }
    }
    __builtin_amdgcn_s_setprio(0);

    __syncthreads();  // all reads of LDS(t) done -> next iter may overwrite
  }

  __bf16* obase = Oa + (size_t)(b * S_ + q0) * E_ + h * D_;
#pragma unroll
  for (int m = 0; m < 2; ++m) {
#pragma unroll
    for (int r = 0; r < 4; ++r) {
      float v = lsum[m][r];
#pragma unroll
      for (int off = 1; off < 16; off <<= 1) v += __shfl_xor(v, off);
      const float inv = 1.0f / v;
#pragma unroll
      for (int dt = 0; dt < 8; ++dt)
        obase[(size_t)(m * 16 + quad * 4 + r) * E_ + dt * 16 + l16] =
            (__bf16)(o[m][dt][r] * inv);
    }
  }
}

// ---------------------------------------------------------------------------
extern "C" void kernel_launch(void* const* d_in, const int* in_sizes, int n_in,
                              void* d_out, int out_size, void* d_ws,
                              size_t ws_size, hipStream_t stream) {
  const float* query = (const float*)d_in[0];
  const float* key   = (const float*)d_in[1];
  const float* value = (const float*)d_in[2];
  const float* mask  = (const float*)d_in[3];
  const float* Wq    = (const float*)d_in[4];
  const float* Wk    = (const float*)d_in[5];
  const float* Wv    = (const float*)d_in[6];
  const float* Wo    = (const float*)d_in[7];
  float* out = (float*)d_out;

  // Workspace 48 MB (known-safe), bf16 elements:
  //   Qp 16MB | Kp 4MB | Vt 4MB | WoT 8MB | WTq 8MB | WTk 2MB | WTv 2MB | sp 4MB
  // Attn (16MB) overlaps [WTq|WTk|WTv|spare] — consumed before attention runs.
  // qb (bf16 query, 16MB) lives in d_out (32MB fp32) — fully overwritten by
  // the final O-projection, consumed before it.
  __bf16* ws   = (__bf16*)d_ws;
  __bf16* Qp   = ws;                           // @ 0
  __bf16* Kp   = Qp + (size_t)NTOK * E_;       // @ 16MB
  __bf16* Vt   = Kp + (size_t)NTOK * KVDIM;    // @ 20MB
  __bf16* WoT  = Vt + (size_t)NTOK * KVDIM;    // @ 24MB
  __bf16* WTq  = WoT + (size_t)E_ * E_;        // @ 32MB
  __bf16* WTk  = WTq + (size_t)E_ * E_;        // @ 40MB
  __bf16* WTv  = WTk + (size_t)KVDIM * E_;     // @ 42MB
  __bf16* Attn = WTq;                          // @ 32MB (16MB, reuse)
  __bf16* qb   = (__bf16*)d_out;               // 16MB scratch in output buf

  // 1) all weight transposes in one launch
  transpose_all<<<dim3(64, 64, 4), 256, 0, stream>>>(Wq, Wk, Wv, Wo,
                                                     WTq, WTk, WTv, WoT);
  // 2) query fp32 -> bf16 (enables global_load_lds A-path in gemm_pipe)
  convert_q<<<dim3(4096), 256, 0, stream>>>(query, qb);
  // 3) K/V projections (old structure, fp32 A), 8x32 = 256 blocks
  gemm_kv<<<dim3(8, 32), 256, 0, stream>>>(key, value, WTk, WTv, Kp, Vt);
  // 4) Q projection via pipelined GEMM: qb @ WTq -> Qp (bf16 epilogue)
  gemm_pipe<<<dim3(E_ / 256, NTOK / 128), 512, 0, stream>>>(
      qb, WTq, nullptr, Qp, NTOK, E_, E_, 1);
  // 5) attention -> Attn (clobbers WTq/k/v, already consumed)
  attn_kernel<<<dim3(S_ / 128, B_ * H_), 256, 0, stream>>>(Qp, Kp, Vt, mask,
                                                           Attn);
  // 6) output projection via pipelined GEMM (fp32 epilogue straight to d_out)
  gemm_pipe<<<dim3(E_ / 256, NTOK / 128), 512, 0, stream>>>(
      Attn, WoT, out, nullptr, NTOK, E_, E_, 0);
}

// Round 5
// 404.216 us; speedup vs baseline: 1.0172x; 1.0101x over previous
//
#include <hip/hip_runtime.h>
#include <hip/hip_bf16.h>

// Problem constants
#define B_    2
#define S_    2048
#define E_    2048
#define H_    16
#define HKV_  4
#define D_    128
#define NTOK  4096      // B_*S_
#define KVDIM 512       // HKV_*D_

typedef __bf16 bf16x8 __attribute__((ext_vector_type(8)));
typedef __bf16 bf16x4 __attribute__((ext_vector_type(4)));
typedef float  f32x4  __attribute__((ext_vector_type(4)));

__device__ __forceinline__ void async_copy16(const void* g, void* l) {
  // 16B per lane; LDS dest = wave-uniform base + lane*16 (m104/m108 semantics)
  __builtin_amdgcn_global_load_lds(
      (const __attribute__((address_space(1))) unsigned int*)g,
      (__attribute__((address_space(3))) unsigned int*)l, 16, 0, 0);
}

// ---------------------------------------------------------------------------
// Fused 4-weight transpose+convert: fp32 [R][C] -> bf16 [C][R], z selects W.
// Round 5: 64x32 tiles, f32x4 coalesced loads, bf16x8 16B coalesced stores
// (old version did scalar 2B stores at 8B stride -> ~70 us for a 60 MB op).
// LDS t[32][65]: write bank = (lc+j+lr) mod 32 (65==1 mod 32) -> <=2-way;
// read bank = (oc+orr+j) mod 32 -> <=2-way. Both free (m136).
// ---------------------------------------------------------------------------
__global__ __launch_bounds__(256) void transpose_all(
    const float* __restrict__ Wq, const float* __restrict__ Wk,
    const float* __restrict__ Wv, const float* __restrict__ Wo,
    __bf16* __restrict__ WTq, __bf16* __restrict__ WTk,
    __bf16* __restrict__ WTv, __bf16* __restrict__ WoT) {
  const float* in;
  __bf16* out;
  int C;
  switch (blockIdx.z) {
    case 0:  in = Wq; out = WTq; C = E_;   break;
    case 1:  in = Wk; out = WTk; C = KVDIM; break;
    case 2:  in = Wv; out = WTv; C = KVDIM; break;
    default: in = Wo; out = WoT; C = E_;   break;
  }
  const int c0 = blockIdx.x * 32;
  if (c0 >= C) return;  // uniform early-exit (idle z=1/2 blocks)
  const int r0 = blockIdx.y * 64;
  __shared__ float t[32][65];            // t[c][r]
  const int lr = threadIdx.x >> 2;       // 0..63 input row
  const int lc = (threadIdx.x & 3) * 8;  // 0,8,16,24 input col
  const float* ip = in + (size_t)(r0 + lr) * C + c0 + lc;
  const f32x4 a0 = *(const f32x4*)ip;
  const f32x4 a1 = *(const f32x4*)(ip + 4);
#pragma unroll
  for (int j = 0; j < 4; ++j) t[lc + j][lr] = a0[j];
#pragma unroll
  for (int j = 0; j < 4; ++j) t[lc + 4 + j][lr] = a1[j];
  __syncthreads();
  const int oc = threadIdx.x >> 3;        // 0..31 output row (c)
  const int orr = (threadIdx.x & 7) * 8;  // 0..56 output col (r)
  bf16x8 v;
#pragma unroll
  for (int j = 0; j < 8; ++j) v[j] = (__bf16)t[oc][orr + j];
  *(bf16x8*)(out + (size_t)(c0 + oc) * E_ + r0 + orr) = v;  // 16B coalesced
}

// ---------------------------------------------------------------------------
// fp32 -> bf16 elementwise convert (query staging for pipelined GEMM).
// ---------------------------------------------------------------------------
__global__ __launch_bounds__(256) void convert_q(const float* __restrict__ in,
                                                 __bf16* __restrict__ ob) {
  const size_t i = ((size_t)blockIdx.x * 256 + threadIdx.x) * 8;
  const f32x4 a0 = *(const f32x4*)(in + i);
  const f32x4 a1 = *(const f32x4*)(in + i + 4);
  bf16x8 v;
#pragma unroll
  for (int j = 0; j < 4; ++j) { v[j] = (__bf16)a0[j]; v[4 + j] = (__bf16)a1[j]; }
  *(bf16x8*)(ob + i) = v;
}

// ---------------------------------------------------------------------------
// Fine-grained pipelined GEMM (unchanged — passed twice, frozen).
// C = A(bf16,[M][K]) @ Bt(bf16,[N][K])^T. BM=128, BN=256, BK=64, 512 thr.
// ---------------------------------------------------------------------------
__global__ __launch_bounds__(512, 1) void gemm_pipe(
    const __bf16* __restrict__ A, const __bf16* __restrict__ Bt,
    float* __restrict__ Cf, __bf16* __restrict__ Cb, int M, int N, int K,
    int epi) {
  // buf layout: [2][A 128*64 | B 256*64] bf16 = 2 * 24576 elems = 96 KB
  __shared__ __align__(16) __bf16 lds[2 * 24576];

  const int n0 = blockIdx.x * 256;
  const int m0 = blockIdx.y * 128;
  const int tid = threadIdx.x;
  const int w = tid >> 6;
  const int lane = tid & 63;
  const int quad = lane >> 4;
  const int l16 = lane & 15;
  const int wm = w >> 2;      // 0..1
  const int wn = w & 3;       // 0..3
  const int lr = lane >> 3;   // 0..7 (staging row within 8-row group)
  const int ls = lane & 7;    // staging 16B slot

  const __bf16* pa[2];
  const __bf16* pb[4];
#pragma unroll
  for (int r = 0; r < 2; ++r) {
    const int row = r * 64 + w * 8 + lr;
    pa[r] = A + (size_t)(m0 + row) * K + ((ls ^ (row & 7)) * 8);
  }
#pragma unroll
  for (int r = 0; r < 4; ++r) {
    const int row = r * 64 + w * 8 + lr;
    pb[r] = Bt + (size_t)(n0 + row) * K + ((ls ^ (row & 7)) * 8);
  }

  auto stageA = [&](int bufi) {
    __bf16* base = lds + bufi * 24576;
#pragma unroll
    for (int r = 0; r < 2; ++r) {
      async_copy16(pa[r], base + (size_t)(r * 64 + w * 8) * 64);
      pa[r] += 64;
    }
  };
  auto stageB = [&](int bufi) {
    __bf16* base = lds + bufi * 24576 + 8192;
#pragma unroll
    for (int r = 0; r < 4; ++r) {
      async_copy16(pb[r], base + (size_t)(r * 64 + w * 8) * 64);
      pb[r] += 64;
    }
  };

  f32x4 acc[4][4] = {};
  const int NT = K >> 6;
  const int xr = l16 & 7;

  stageA(0);            // 2 loads
  stageB(0);            // 4 loads
  stageB(1);            // 4 loads
  asm volatile("s_waitcnt vmcnt(4)" ::: "memory");  // tile0 landed
  __builtin_amdgcn_s_barrier();

  for (int t = 0; t < NT; ++t) {
    const __bf16* lA = lds + (t & 1) * 24576;
    const __bf16* lB = lA + 8192;

    // ======== P0: f-half 0 ========
    bf16x8 af[2][2], bfr[4][2];
#pragma unroll
    for (int f = 0; f < 2; ++f) {
      const int rowb = (wm * 64 + f * 16 + l16) * 64;
#pragma unroll
      for (int ks = 0; ks < 2; ++ks)
        af[f][ks] = *(const bf16x8*)&lA[rowb + (((ks * 4 + quad) ^ xr) * 8)];
    }
#pragma unroll
    for (int g = 0; g < 4; ++g) {
      const int rowb = (wn * 64 + g * 16 + l16) * 64;
#pragma unroll
      for (int ks = 0; ks < 2; ++ks)
        bfr[g][ks] = *(const bf16x8*)&lB[rowb + (((ks * 4 + quad) ^ xr) * 8)];
    }
    if (t + 1 < NT) stageA((t + 1) & 1);  // A region of other buf is free
    __builtin_amdgcn_s_barrier();
    asm volatile("s_waitcnt lgkmcnt(0)" ::: "memory");
    __builtin_amdgcn_sched_barrier(0);
    __builtin_amdgcn_s_setprio(1);
#pragma unroll
    for (int f = 0; f < 2; ++f)
#pragma unroll
      for (int g = 0; g < 4; ++g) {
        acc[f][g] = __builtin_amdgcn_mfma_f32_16x16x32_bf16(af[f][0], bfr[g][0],
                                                            acc[f][g], 0, 0, 0);
        acc[f][g] = __builtin_amdgcn_mfma_f32_16x16x32_bf16(af[f][1], bfr[g][1],
                                                            acc[f][g], 0, 0, 0);
      }
    __builtin_amdgcn_s_setprio(0);
    __builtin_amdgcn_s_barrier();  // closes B region of buf[t&1]

    // ======== P1: f-half 1 ========
    bf16x8 ah[2][2];
#pragma unroll
    for (int f = 0; f < 2; ++f) {
      const int rowb = (wm * 64 + (f + 2) * 16 + l16) * 64;
#pragma unroll
      for (int ks = 0; ks < 2; ++ks)
        ah[f][ks] = *(const bf16x8*)&lA[rowb + (((ks * 4 + quad) ^ xr) * 8)];
    }
    if (t + 2 < NT) stageB(t & 1);  // B region of buf[t&1] freed by P0 close
    __builtin_amdgcn_s_barrier();
    asm volatile("s_waitcnt lgkmcnt(0)" ::: "memory");
    __builtin_amdgcn_sched_barrier(0);
    __builtin_amdgcn_s_setprio(1);
#pragma unroll
    for (int f = 0; f < 2; ++f)
#pragma unroll
      for (int g = 0; g < 4; ++g) {
        acc[f + 2][g] = __builtin_amdgcn_mfma_f32_16x16x32_bf16(
            ah[f][0], bfr[g][0], acc[f + 2][g], 0, 0, 0);
        acc[f + 2][g] = __builtin_amdgcn_mfma_f32_16x16x32_bf16(
            ah[f][1], bfr[g][1], acc[f + 2][g], 0, 0, 0);
      }
    __builtin_amdgcn_s_setprio(0);

    if (t + 2 < NT) {
      asm volatile("s_waitcnt vmcnt(4)" ::: "memory");
      __builtin_amdgcn_s_barrier();
    } else if (t + 1 < NT) {
      asm volatile("s_waitcnt vmcnt(0)" ::: "memory");
      __builtin_amdgcn_s_barrier();
    }
  }

  // C/D layout: col = lane&15 (n), row = quad*4 + reg (m). [m89/m91]
#pragma unroll
  for (int f = 0; f < 4; ++f) {
#pragma unroll
    for (int g = 0; g < 4; ++g) {
#pragma unroll
      for (int r = 0; r < 4; ++r) {
        const int m = m0 + wm * 64 + f * 16 + quad * 4 + r;
        const int n = n0 + wn * 64 + g * 16 + l16;
        if (epi == 0) Cf[(size_t)m * N + n] = acc[f][g][r];
        else          Cb[(size_t)m * N + n] = (__bf16)acc[f][g][r];
      }
    }
  }
}

// ---------------------------------------------------------------------------
// K/V projection (m97-style kernel, fp32 A converted during staging; frozen).
// ---------------------------------------------------------------------------
__global__ __launch_bounds__(256, 2) void gemm_kv(
    const float* __restrict__ key, const float* __restrict__ value,
    const __bf16* __restrict__ WTk, const __bf16* __restrict__ WTv,
    __bf16* __restrict__ Kp, __bf16* __restrict__ Vt) {
  __shared__ __align__(16) __bf16 As[128 * 32];
  __shared__ __align__(16) __bf16 Bs[128 * 32];

  const int bx = blockIdx.x;  // 0..7
  const float* A;
  const __bf16* Bt;
  int n0, epi;
  if (bx < 4) { A = key;   Bt = WTk; n0 = bx * 128;       epi = 0; }
  else        { A = value; Bt = WTv; n0 = (bx - 4) * 128; epi = 1; }
  const int m0 = blockIdx.y * 128;
  const int K = E_;
  const int N = KVDIM;

  const int tid = threadIdx.x;
  const int w = tid >> 6;
  const int lane = tid & 63;
  const int quad = lane >> 4;
  const int l16 = lane & 15;
  const int wr = w >> 1, wc = w & 1;
  const int brow = lane >> 2;
  const int bcol = (lane & 3) * 8;
  const int arow = lane >> 2;
  const int acol = (lane & 3) * 8;

  f32x4 acc[4][4] = {};

  for (int k0 = 0; k0 < K; k0 += 32) {
    __syncthreads();
#pragma unroll
    for (int c = 0; c < 2; ++c) {
      const int chunk = w * 2 + c;
      const int row = chunk * 16 + brow;
      async_copy16(Bt + (size_t)(n0 + row) * K + k0 + bcol, &Bs[chunk * 512]);
    }
#pragma unroll
    for (int s = 0; s < 2; ++s) {
      const int row = w * 32 + s * 16 + arow;
      const float* src = A + (size_t)(m0 + row) * K + k0 + acol;
      const f32x4 a0 = *(const f32x4*)src;
      const f32x4 a1 = *(const f32x4*)(src + 4);
      bf16x8 v;
#pragma unroll
      for (int j = 0; j < 4; ++j) { v[j] = (__bf16)a0[j]; v[4 + j] = (__bf16)a1[j]; }
      *(bf16x8*)&As[row * 32 + acol] = v;
    }
    __syncthreads();
    bf16x8 af[4], bfr[4];
#pragma unroll
    for (int i = 0; i < 4; ++i)
      af[i] = *(const bf16x8*)&As[(wr * 64 + i * 16 + l16) * 32 + quad * 8];
#pragma unroll
    for (int j = 0; j < 4; ++j)
      bfr[j] = *(const bf16x8*)&Bs[(wc * 64 + j * 16 + l16) * 32 + quad * 8];
#pragma unroll
    for (int i = 0; i < 4; ++i)
#pragma unroll
      for (int j = 0; j < 4; ++j)
        acc[i][j] = __builtin_amdgcn_mfma_f32_16x16x32_bf16(af[i], bfr[j],
                                                            acc[i][j], 0, 0, 0);
  }

#pragma unroll
  for (int i = 0; i < 4; ++i) {
#pragma unroll
    for (int j = 0; j < 4; ++j) {
#pragma unroll
      for (int r = 0; r < 4; ++r) {
        const int m = m0 + wr * 64 + i * 16 + quad * 4 + r;
        const int n = n0 + wc * 64 + j * 16 + l16;
        if (epi == 0) {
          Kp[(size_t)m * N + n] = (__bf16)acc[i][j][r];
        } else {
          const int b = m >> 11, s = m & (S_ - 1);
          Vt[((size_t)((b * HKV_ + (n >> 7)) * D_ + (n & (D_ - 1)))) * S_ + s] =
              (__bf16)acc[i][j][r];
        }
      }
    }
  }
}

// ---------------------------------------------------------------------------
// Flash attention: block = 128 q-rows of one (b,h). T14 staging kept.
// Round 5: (a) P_lds column-rotate swizzle — write col ^= (quad>>1)<<5,
// read inverse via ks2 ^ (l16>>3): kills the 4-way quad-pair write conflict
// (rows +4 => +16 banks mod 32, so quads {0,2}/{1,3} collided; XOR-32 moves
// them to disjoint 8-dword slots). b128 alignment preserved (XOR on 64B).
// (b) mask prefetched in fetch() — 4 L2 loads/tile hidden with K/V fetch.
// ---------------------------------------------------------------------------
__global__ __launch_bounds__(256, 2) void attn_kernel(
    const __bf16* __restrict__ Q, const __bf16* __restrict__ Kp,
    const __bf16* __restrict__ Vt, const float* __restrict__ mask,
    __bf16* __restrict__ Oa) {
  __shared__ __align__(16) __bf16 K_lds[64][136];
  __shared__ __align__(16) __bf16 V_lds[128][72];
  __shared__ __align__(16) __bf16 P_lds[4][32][72];

  const int tid = threadIdx.x;
  const int w = tid >> 6, lane = tid & 63, quad = lane >> 4, l16 = lane & 15;
  const int bh = blockIdx.y;
  const int b = bh >> 4, h = bh & 15, hkv = h >> 2;
  const int q0 = blockIdx.x * 128 + w * 32;

  const __bf16* qbase = Q + (size_t)(b * S_ + q0) * E_ + h * D_;
  bf16x8 qf[2][4];
#pragma unroll
  for (int m = 0; m < 2; ++m)
#pragma unroll
    for (int ks = 0; ks < 4; ++ks)
      qf[m][ks] = *(const bf16x8*)(qbase + (size_t)(m * 16 + l16) * E_ +
                                   ks * 32 + quad * 8);

  const __bf16* kbase = Kp + (size_t)(b * S_) * KVDIM + hkv * D_;
  const __bf16* vbase = Vt + (size_t)((b * HKV_ + hkv) * D_) * S_;
  const float* mbase = mask + b * S_;

  // Staging geometry (T14 split issue/write):
  const int kr = w * 16 + (lane >> 4);        // K row base (+i*4)
  const int kc = (lane & 15) * 8;             // K col
  const int vr = w * 32 + (lane >> 3);        // V row base (+i*8)
  const int vc = (lane & 7) * 8;              // V col (within kt tile)
  const int psw = (quad >> 1) << 5;           // P write col swizzle
  const int pks = l16 >> 3;                   // P read ks2 flip

  bf16x8 kreg[4], vreg[4];
  float mreg[4];
  auto fetch = [&](int kt) {
#pragma unroll
    for (int i = 0; i < 4; ++i)
      kreg[i] = *(const bf16x8*)(kbase + (size_t)(kt + kr + i * 4) * KVDIM + kc);
#pragma unroll
    for (int i = 0; i < 4; ++i)
      vreg[i] = *(const bf16x8*)(vbase + (size_t)(vr + i * 8) * S_ + kt + vc);
#pragma unroll
    for (int n = 0; n < 4; ++n)
      mreg[n] = mbase[kt + n * 16 + l16];
  };

  f32x4 o[2][8] = {};
  f32x4 lsum[2] = {};
  const float scale = 0.08838834764831845f;  // 1/sqrt(128)

  fetch(0);  // prologue prefetch (K, V, mask for tile 0)

  for (int kt = 0; kt < S_; kt += 64) {
    // write current tile's regs -> LDS (prev iter's read-sync guarantees safe)
#pragma unroll
    for (int i = 0; i < 4; ++i)
      *(bf16x8*)&K_lds[kr + i * 4][kc] = kreg[i];
#pragma unroll
    for (int i = 0; i < 4; ++i)
      *(bf16x8*)&V_lds[vr + i * 8][vc] = vreg[i];
    // consume this tile's mask BEFORE fetch() overwrites mreg
    float bias[4];
#pragma unroll
    for (int n = 0; n < 4; ++n)
      bias[n] = (1.0f - mreg[n]) * -1e9f;
    __syncthreads();  // LDS(t) visible to all

    // T14: issue next tile's global loads NOW — hidden under compute below
    if (kt + 64 < S_) fetch(kt + 64);

    f32x4 s[2][4] = {};
    __builtin_amdgcn_s_setprio(1);
#pragma unroll
    for (int ks = 0; ks < 4; ++ks) {
#pragma unroll
      for (int n = 0; n < 4; ++n) {
        bf16x8 kf = *(const bf16x8*)&K_lds[n * 16 + l16][ks * 32 + quad * 8];
        s[0][n] = __builtin_amdgcn_mfma_f32_16x16x32_bf16(qf[0][ks], kf,
                                                          s[0][n], 0, 0, 0);
        s[1][n] = __builtin_amdgcn_mfma_f32_16x16x32_bf16(qf[1][ks], kf,
                                                          s[1][n], 0, 0, 0);
      }
    }
    __builtin_amdgcn_s_setprio(0);

#pragma unroll
    for (int m = 0; m < 2; ++m) {
#pragma unroll
      for (int n = 0; n < 4; ++n) {
#pragma unroll
        for (int r = 0; r < 4; ++r) {
          const float p = __expf(s[m][n][r] * scale + bias[n]);
          lsum[m][r] += p;
          P_lds[w][m * 16 + quad * 4 + r][(n * 16 + l16) ^ psw] = (__bf16)p;
        }
      }
    }

    __builtin_amdgcn_s_setprio(1);
#pragma unroll
    for (int ks2 = 0; ks2 < 2; ++ks2) {
      bf16x8 pa[2];
#pragma unroll
      for (int m = 0; m < 2; ++m)
        pa[m] = *(const bf16x8*)
            &P_lds[w][m * 16 + l16][(ks2 ^ pks) * 32 + quad * 8];
#pragma unroll
      for (int dt = 0; dt < 8; ++dt) {
        bf16x8 vf = *(const bf16x8*)&V_lds[dt * 16 + l16][ks2 * 32 + quad * 8];
        o[0][dt] = __builtin_amdgcn_mfma_f32_16x16x32_bf16(pa[0], vf,
                                                           o[0][dt], 0, 0, 0);
        o[1][dt] = __builtin_amdgcn_mfma_f32_16x16x32_bf16(pa[1], vf,
                                                           o[1][dt], 0, 0, 0);
      }
    }
    __builtin_amdgcn_s_setprio(0);

    __syncthreads();  // all reads of LDS(t) done -> next iter may overwrite
  }

  __bf16* obase = Oa + (size_t)(b * S_ + q0) * E_ + h * D_;
#pragma unroll
  for (int m = 0; m < 2; ++m) {
#pragma unroll
    for (int r = 0; r < 4; ++r) {
      float v = lsum[m][r];
#pragma unroll
      for (int off = 1; off < 16; off <<= 1) v += __shfl_xor(v, off);
      const float inv = 1.0f / v;
#pragma unroll
      for (int dt = 0; dt < 8; ++dt)
        obase[(size_t)(m * 16 + quad * 4 + r) * E_ + dt * 16 + l16] =
            (__bf16)(o[m][dt][r] * inv);
    }
  }
}

// ---------------------------------------------------------------------------
extern "C" void kernel_launch(void* const* d_in, const int* in_sizes, int n_in,
                              void* d_out, int out_size, void* d_ws,
                              size_t ws_size, hipStream_t stream) {
  const float* query = (const float*)d_in[0];
  const float* key   = (const float*)d_in[1];
  const float* value = (const float*)d_in[2];
  const float* mask  = (const float*)d_in[3];
  const float* Wq    = (const float*)d_in[4];
  const float* Wk    = (const float*)d_in[5];
  const float* Wv    = (const float*)d_in[6];
  const float* Wo    = (const float*)d_in[7];
  float* out = (float*)d_out;

  // Workspace 48 MB (known-safe), bf16 elements:
  //   Qp 16MB | Kp 4MB | Vt 4MB | WoT 8MB | WTq 8MB | WTk 2MB | WTv 2MB | sp 4MB
  // Attn (16MB) overlaps [WTq|WTk|WTv|spare] — consumed before attention runs.
  // qb (bf16 query, 16MB) lives in d_out (32MB fp32) — fully overwritten by
  // the final O-projection, consumed before it.
  __bf16* ws   = (__bf16*)d_ws;
  __bf16* Qp   = ws;                           // @ 0
  __bf16* Kp   = Qp + (size_t)NTOK * E_;       // @ 16MB
  __bf16* Vt   = Kp + (size_t)NTOK * KVDIM;    // @ 20MB
  __bf16* WoT  = Vt + (size_t)NTOK * KVDIM;    // @ 24MB
  __bf16* WTq  = WoT + (size_t)E_ * E_;        // @ 32MB
  __bf16* WTk  = WTq + (size_t)E_ * E_;        // @ 40MB
  __bf16* WTv  = WTk + (size_t)KVDIM * E_;     // @ 42MB
  __bf16* Attn = WTq;                          // @ 32MB (16MB, reuse)
  __bf16* qb   = (__bf16*)d_out;               // 16MB scratch in output buf

  // 1) all weight transposes in one launch (64x32 tiles now)
  transpose_all<<<dim3(64, 32, 4), 256, 0, stream>>>(Wq, Wk, Wv, Wo,
                                                     WTq, WTk, WTv, WoT);
  // 2) query fp32 -> bf16 (enables global_load_lds A-path in gemm_pipe)
  convert_q<<<dim3(4096), 256, 0, stream>>>(query, qb);
  // 3) K/V projections (old structure, fp32 A), 8x32 = 256 blocks
  gemm_kv<<<dim3(8, 32), 256, 0, stream>>>(key, value, WTk, WTv, Kp, Vt);
  // 4) Q projection via pipelined GEMM: qb @ WTq -> Qp (bf16 epilogue)
  gemm_pipe<<<dim3(E_ / 256, NTOK / 128), 512, 0, stream>>>(
      qb, WTq, nullptr, Qp, NTOK, E_, E_, 1);
  // 5) attention -> Attn (clobbers WTq/k/v, already consumed)
  attn_kernel<<<dim3(S_ / 128, B_ * H_), 256, 0, stream>>>(Qp, Kp, Vt, mask,
                                                           Attn);
  // 6) output projection via pipelined GEMM (fp32 epilogue straight to d_out)
  gemm_pipe<<<dim3(E_ / 256, NTOK / 128), 512, 0, stream>>>(
      Attn, WoT, out, nullptr, NTOK, E_, E_, 0);
}